// Round 16
// baseline (896.955 us; speedup 1.0000x reference)
//
#include <hip/hip_runtime.h>
#include <cstdint>
#include <cstddef>

#define INDIM 512
#define HIDD  256
#define OUTD  32
#define PCH   4096      // edges per radix block
#define SHIFT 9
#define SLABN 512       // nodes per slab; nslab <= 256

typedef __attribute__((ext_vector_type(4))) float f32x4;
typedef __attribute__((ext_vector_type(8))) short bf16x8;

// ---- bf16 <-> f32 helpers ----
static inline __device__ float b2f(unsigned short u) {
  union { float f; unsigned int i; } v; v.i = ((unsigned int)u) << 16; return v.f;
}
static inline __device__ unsigned short f2b(float f) {
  union { float f; unsigned int i; } v; v.f = f;
  unsigned int x = v.i;
  x += 0x7fffu + ((x >> 16) & 1u);   // round-to-nearest-even
  return (unsigned short)(x >> 16);
}

// edge weight: exp(sigmoid(x)) — SAME formula in both agg kernels
static inline __device__ float edgew(float x) {
  float al = 1.f / (1.f + __expf(-x));
  return __expf(al);
}

// async global->LDS, 16B per lane. LDS dest = wave-uniform base + lane*16.
static __device__ __forceinline__ void gld16(const unsigned short* g, unsigned short* l) {
  __builtin_amdgcn_global_load_lds(
      (const __attribute__((address_space(1))) void*)g,
      (__attribute__((address_space(3))) void*)l, 16, 0, 0);
}

// ---- runtime dtype probe ----
__global__ __launch_bounds__(256) void probe_kernel(
    const unsigned int* __restrict__ feat, const unsigned int* __restrict__ eidx,
    int* __restrict__ flags)
{
  int t = threadIdx.x;
  __shared__ int cnt, oddnz;
  if (t == 0) { cnt = 0; oddnz = 0; }
  __syncthreads();
  unsigned int w = feat[t];
  unsigned short lo = (unsigned short)(w & 0xFFFFu);
  int e = (lo >> 7) & 0xFF;
  int plausible = ((lo & 0x7FFF) == 0) || (e >= 0x60 && e <= 0x9F);
  atomicAdd(&cnt, plausible);
  if (t & 1) { if (eidx[t] != 0u) atomicAdd(&oddnz, 1); }
  __syncthreads();
  if (t == 0) { flags[0] = (cnt >= 192) ? 1 : 0; flags[1] = (oddnz == 0) ? 1 : 0; }
}

// ---- radix pass A: per-block slab counts (LDS hist, plain global writes) ----
__global__ __launch_bounds__(256) void cnt_kernel(
    const unsigned int* __restrict__ eidx, int* __restrict__ bcnt,
    int E, const int* __restrict__ flags)
{
  __shared__ int hist[256];
  int t = threadIdx.x;
  hist[t] = 0;
  __syncthreads();
  int e0 = blockIdx.x * PCH;
  const int i64 = flags[1];
  for (int i = t; i < PCH; i += 256) {
    int e = e0 + i; if (e >= E) break;
    int d = i64 ? (int)eidx[2 * ((size_t)E + e)] : (int)eidx[(size_t)E + e];
    atomicAdd(&hist[d >> SHIFT], 1);
  }
  __syncthreads();
  bcnt[blockIdx.x * 256 + t] = hist[t];
}

// ---- radix pass B: bcnt -> within-slab block prefixes; slabOff excl scan ----
__global__ __launch_bounds__(256) void bscan_kernel(
    int* __restrict__ bcnt, int* __restrict__ slabOff, int npb)
{
  __shared__ int wsum[4];
  int t = threadIdx.x, lane = t & 63, wv = t >> 6;
  int run = 0;
  for (int b = 0; b < npb; ++b) {
    int v = bcnt[b * 256 + t];
    bcnt[b * 256 + t] = run;     // within-slab prefix
    run += v;
  }
  int inc = run;
#pragma unroll
  for (int o = 1; o < 64; o <<= 1) {
    int u = __shfl_up(inc, o);
    if (lane >= o) inc += u;
  }
  if (lane == 63) wsum[wv] = inc;
  __syncthreads();
  if (t < 4) {
    int v = wsum[t], s = v;
#pragma unroll
    for (int o = 1; o < 4; o <<= 1) {
      int u = __shfl_up(s, o);
      if (t >= o) s += u;
    }
    wsum[t] = s - v;
  }
  __syncthreads();
  int exc = wsum[wv] + inc - run;
  slabOff[t] = exc;
  if (t == 255) slabOff[256] = exc + run;   // = E
}

// ---- radix pass C: scatter (src,dst) into slab-contiguous part[] ----
__global__ __launch_bounds__(256) void scat_kernel(
    const unsigned int* __restrict__ eidx, const int* __restrict__ bcnt,
    const int* __restrict__ slabOff, uint2* __restrict__ part,
    int E, const int* __restrict__ flags)
{
  __shared__ int cur[256];
  int t = threadIdx.x;
  cur[t] = slabOff[t] + bcnt[blockIdx.x * 256 + t];
  __syncthreads();
  int e0 = blockIdx.x * PCH;
  const int i64 = flags[1];
  for (int i = t; i < PCH; i += 256) {
    int e = e0 + i; if (e >= E) break;
    int s, d;
    if (i64) { s = (int)eidx[2 * (size_t)e]; d = (int)eidx[2 * ((size_t)E + e)]; }
    else     { s = (int)eidx[e];             d = (int)eidx[(size_t)E + e]; }
    int pos = atomicAdd(&cur[d >> SHIFT], 1);
    part[pos] = make_uint2((unsigned)s, (unsigned)d);
  }
}

// ---- radix pass D: per-slab CSR build fully in LDS (deg, scan, fill) ----
__global__ __launch_bounds__(256) void slabcsr_kernel(
    const uint2* __restrict__ part, const int* __restrict__ slabOff,
    int* __restrict__ offs, int* __restrict__ srcP, int N, int nslab)
{
  __shared__ int deg[SLABN];
  __shared__ int wsum[4];
  int sl = blockIdx.x, t = threadIdx.x;
  int n0 = sl << SHIFT;
  int nn = N - n0; if (nn > SLABN) nn = SLABN;
  int s0 = slabOff[sl], s1 = slabOff[sl + 1];
  for (int i = t; i < SLABN; i += 256) deg[i] = 0;
  __syncthreads();
  for (int i = s0 + t; i < s1; i += 256)
    atomicAdd(&deg[(int)part[i].y - n0], 1);
  __syncthreads();
  int bi = t * 2;
  int l0 = deg[bi], l1 = deg[bi + 1];
  int s = l0 + l1;
  int ws = s;
#pragma unroll
  for (int o = 1; o < 64; o <<= 1) {
    int u = __shfl_up(ws, o);
    if ((t & 63) >= o) ws += u;
  }
  if ((t & 63) == 63) wsum[t >> 6] = ws;
  __syncthreads();
  if (t < 4) {
    int v = wsum[t], inc = v;
#pragma unroll
    for (int o = 1; o < 4; o <<= 1) {
      int u = __shfl_up(inc, o);
      if (t >= o) inc += u;
    }
    wsum[t] = inc - v;
  }
  __syncthreads();
  int run = wsum[t >> 6] + (ws - s);   // thread-exclusive base
  deg[bi] = run;
  if (bi < nn) offs[n0 + bi] = s0 + run;
  run += l0;
  deg[bi + 1] = run;
  if (bi + 1 < nn) offs[n0 + bi + 1] = s0 + run;
  __syncthreads();
  for (int i = s0 + t; i < s1; i += 256) {
    uint2 p = part[i];
    int pos = s0 + atomicAdd(&deg[(int)p.y - n0], 1);
    srcP[pos] = (int)p.x;
  }
  if (sl == nslab - 1 && t == 0) offs[N] = s1;
}

static inline __device__ float ldadapt(const void* p, size_t i, int isbf) {
  return isbf ? b2f(((const unsigned short*)p)[i]) : ((const float*)p)[i];
}

// ---- weight prep: W1b, W1tb (bf16), W2f (f32), att (f32) ----
__global__ __launch_bounds__(256) void prep_weights(
    const void* __restrict__ W1, const void* __restrict__ W2,
    const void* __restrict__ aS, const void* __restrict__ aD,
    unsigned short* __restrict__ W1b, unsigned short* __restrict__ W1tb,
    float* __restrict__ W2f,
    float* __restrict__ atS, float* __restrict__ atD,
    const int* __restrict__ flags)
{
  const int fb = flags[0];
  int i = blockIdx.x * 256 + threadIdx.x;
  if (i < INDIM * HIDD) {               // W1: [512][256]
    int r = i >> 8, c = i & 255;
    float w0 = ldadapt(W1, i, fb);
    unsigned short wb = f2b(w0);
    W1b[i] = wb;                        // Bt for h4: [512 rows][256 k]
    W1tb[c * INDIM + r] = wb;           // Bt for xp1: [256 rows][512 k]
  }
  if (i < HIDD * OUTD) W2f[i] = ldadapt(W2, i, fb);
  if (i < HIDD) { atS[i] = ldadapt(aS, i, fb); atD[i] = ldadapt(aD, i, fb); }
}

// =====================================================================
// MFMA NT GEMM, BM=128 x BN=256, BK=64, 512 threads = 8 waves (2x4 of
// 64x64). T2 swizzle (rule #21 form). Single-buffered (r14 dbuf neutral).
// AMODE:   0 = A bf16 ws buffer; 1 = A external: fb ? bf16 : f32 reg-staged
// OUTMODE: 0 = bf16 to Cb; 1 = adaptive (flags[0]) to Out+outOff
// EPI:     0 = none; 1 = ELU before store
// DOTS:    1 = also emit asrc/adst row-dots vs atS/atD (requires grid.x==1)
// =====================================================================
template<int AMODE, int OUTMODE, int EPI, int DOTS>
__global__ __launch_bounds__(512, 4) void gemm_nt2(
    const void* __restrict__ Av, const unsigned short* __restrict__ Bt,
    unsigned short* __restrict__ Cb, void* __restrict__ Out, size_t outOff,
    const float* __restrict__ atS, const float* __restrict__ atD,
    float* __restrict__ asrc, float* __restrict__ adst,
    const int* __restrict__ flags, int M, int Nn, int K)
{
  __shared__ unsigned short Als[128 * 64];   // 16 KB
  __shared__ unsigned short Bls[256 * 64];   // 32 KB
  __shared__ float sdot[2][128];             // 1 KB (DOTS only)
  const int tid = threadIdx.x, lane = tid & 63, wid = tid >> 6;   // 8 waves
  const int wr = wid >> 2, wc = wid & 3;     // 2x4 wave grid, 64x64 each
  const int rowBase = blockIdx.y * 128, colBase = blockIdx.x * 256;
  const int fb = flags[0];

  const int srow = (lane >> 3), sg = lane & 7;
  const int sgx = sg ^ srow;                 // inverse-swizzled source granule

  f32x4 acc[4][4] = {};

  for (int kt = 0; kt < K; kt += 64) {
    // ---- stage A: 16 chunks (1KB = 8 rows), 2 per wave ----
    if (AMODE == 1 && !fb) {
      const float* Af = (const float*)Av;
#pragma unroll
      for (int i = 0; i < 2; ++i) {
        int row = wid * 16 + i * 8 + srow;
        int gr = rowBase + row; if (gr > M - 1) gr = M - 1;
        const float* sp = Af + (size_t)gr * K + kt + sg * 8;   // linear coalesced
        float4 lo = *(const float4*)sp;
        float4 hi = *(const float4*)(sp + 4);
        union { unsigned short us[8]; int4 v; } cv;
        cv.us[0] = f2b(lo.x); cv.us[1] = f2b(lo.y); cv.us[2] = f2b(lo.z); cv.us[3] = f2b(lo.w);
        cv.us[4] = f2b(hi.x); cv.us[5] = f2b(hi.y); cv.us[6] = f2b(hi.z); cv.us[7] = f2b(hi.w);
        *(int4*)(Als + row * 64 + (sgx << 3)) = cv.v;          // swizzled ds_write
      }
    } else {
      const unsigned short* Ab = (const unsigned short*)Av;
#pragma unroll
      for (int i = 0; i < 2; ++i) {
        int row = wid * 16 + i * 8 + srow;
        int gr = rowBase + row;
        if (AMODE == 1 && gr > M - 1) gr = M - 1;   // external input: clamp
        gld16(Ab + (size_t)gr * K + kt + (sgx << 3), Als + (wid * 2 + i) * 512);
      }
    }
    // ---- stage B: 32 chunks, 4 per wave ----
#pragma unroll
    for (int i = 0; i < 4; ++i) {
      int row = wid * 32 + i * 8 + srow;
      gld16(Bt + (size_t)(colBase + row) * K + kt + (sgx << 3), Bls + (wid * 4 + i) * 512);
    }
    __syncthreads();

    bf16x8 af[4], bfr[4];
#pragma unroll
    for (int ks = 0; ks < 2; ++ks) {
      int gl = ks * 4 + (lane >> 4);
      int gx = gl ^ (lane & 7);        // row&7 == lane&7 for fragment rows
#pragma unroll
      for (int mi = 0; mi < 4; ++mi) {
        int row = wr * 64 + mi * 16 + (lane & 15);
        af[mi] = *(const bf16x8*)(Als + row * 64 + (gx << 3));
      }
#pragma unroll
      for (int ni = 0; ni < 4; ++ni) {
        int row = wc * 64 + ni * 16 + (lane & 15);
        bfr[ni] = *(const bf16x8*)(Bls + row * 64 + (gx << 3));
      }
#pragma unroll
      for (int mi = 0; mi < 4; ++mi)
#pragma unroll
        for (int ni = 0; ni < 4; ++ni)
          acc[mi][ni] = __builtin_amdgcn_mfma_f32_16x16x32_bf16(af[mi], bfr[ni], acc[mi][ni], 0, 0, 0);
    }
    __syncthreads();
  }

  // C/D: col = lane&15, row = (lane>>4)*4 + reg
#pragma unroll
  for (int mi = 0; mi < 4; ++mi) {
    int r0 = rowBase + wr * 64 + mi * 16 + (lane >> 4) * 4;
#pragma unroll
    for (int ni = 0; ni < 4; ++ni) {
      int c = colBase + wc * 64 + ni * 16 + (lane & 15);
#pragma unroll
      for (int v = 0; v < 4; ++v) {
        int r = r0 + v;
        if (r < M) {
          size_t idx = (size_t)r * Nn + c;
          float x = acc[mi][ni][v];
          if (EPI) x = x > 0.f ? x : expm1f(x);
          if (OUTMODE == 0) Cb[idx] = f2b(x);
          else {
            if (fb) ((unsigned short*)Out)[outOff + idx] = f2b(x);
            else    ((float*)Out)[outOff + idx] = x;
          }
        }
      }
    }
  }

  // ---- fused rowdots epilogue (xp1 only): asrc/adst from f32 accumulators ----
  if (DOTS) {
    if (tid < 128) { sdot[0][tid] = 0.f; sdot[1][tid] = 0.f; }
    __syncthreads();
    float vS[4], vD[4];
#pragma unroll
    for (int ni = 0; ni < 4; ++ni) {
      int c = colBase + wc * 64 + ni * 16 + (lane & 15);
      vS[ni] = atS[c]; vD[ni] = atD[c];
    }
#pragma unroll
    for (int mi = 0; mi < 4; ++mi) {
#pragma unroll
      for (int v = 0; v < 4; ++v) {
        float ps = 0.f, pd = 0.f;
#pragma unroll
        for (int ni = 0; ni < 4; ++ni) {
          ps += acc[mi][ni][v] * vS[ni];
          pd += acc[mi][ni][v] * vD[ni];
        }
#pragma unroll
        for (int off = 1; off < 16; off <<= 1) {
          ps += __shfl_xor(ps, off);
          pd += __shfl_xor(pd, off);
        }
        if ((lane & 15) == 0) {
          int rl = wr * 64 + mi * 16 + (lane >> 4) * 4 + v;
          atomicAdd(&sdot[0][rl], ps);   // combine the 4 column-waves
          atomicAdd(&sdot[1][rl], pd);
        }
      }
    }
    __syncthreads();
    if (tid < 128) {
      int r = rowBase + tid;
      if (r < M) { asrc[r] = sdot[0][tid]; adst[r] = sdot[1][tid]; }
    }
  }
}

// ---- agg layer 1: wave/node, 16 gathers in flight, denominator in-loop ----
__global__ __launch_bounds__(256) void agg_elu2(
    const unsigned short* __restrict__ xp,
    const float* __restrict__ asrc, const float* __restrict__ adst,
    const int* __restrict__ srcP, const int* __restrict__ offs,
    unsigned short* __restrict__ hout, int N)
{
  __shared__ int   sS[4][64];
  __shared__ float sW[4][64];
  int wid = threadIdx.x >> 6, lane = threadIdx.x & 63;
  int node = blockIdx.x * 4 + wid;
  if (node >= N) return;
  const float ad = adst[node];
  int s0 = offs[node], s1 = offs[node + 1];
  float a0 = 0.f, a1 = 0.f, a2 = 0.f, a3 = 0.f, den = 0.f;
  for (int base = s0; base < s1; base += 64) {
    int cnt = s1 - base; if (cnt > 64) cnt = 64;
    if (lane < cnt) {
      int sv = srcP[base + lane];
      sS[wid][lane] = sv;
      sW[wid][lane] = edgew(asrc[sv] + ad);
    }
    asm volatile("s_waitcnt lgkmcnt(0)" ::: "memory");   // wave-local LDS RAW fence
    int j = 0;
    for (; j + 16 <= cnt; j += 16) {          // 16 gathers in flight
      ushort4 u[16];
#pragma unroll
      for (int q = 0; q < 16; ++q)
        u[q] = *(const ushort4*)(xp + (size_t)sS[wid][j + q] * HIDD + lane * 4);
#pragma unroll
      for (int q = 0; q < 16; ++q) {
        float wv = sW[wid][j + q];
        den += wv;
        a0 += wv * b2f(u[q].x); a1 += wv * b2f(u[q].y);
        a2 += wv * b2f(u[q].z); a3 += wv * b2f(u[q].w);
      }
    }
    for (; j + 8 <= cnt; j += 8) {
      ushort4 u[8];
#pragma unroll
      for (int q = 0; q < 8; ++q)
        u[q] = *(const ushort4*)(xp + (size_t)sS[wid][j + q] * HIDD + lane * 4);
#pragma unroll
      for (int q = 0; q < 8; ++q) {
        float wv = sW[wid][j + q];
        den += wv;
        a0 += wv * b2f(u[q].x); a1 += wv * b2f(u[q].y);
        a2 += wv * b2f(u[q].z); a3 += wv * b2f(u[q].w);
      }
    }
    for (; j < cnt; ++j) {
      int   sv = sS[wid][j];
      float wv = sW[wid][j];
      den += wv;
      ushort4 u = *(const ushort4*)(xp + (size_t)sv * HIDD + lane * 4);
      a0 += wv * b2f(u.x); a1 += wv * b2f(u.y); a2 += wv * b2f(u.z); a3 += wv * b2f(u.w);
    }
  }
  float inv = 1.f / (den + 1e-16f);
  float r0 = a0 * inv, r1 = a1 * inv, r2 = a2 * inv, r3 = a3 * inv;
  r0 = r0 > 0.f ? r0 : expm1f(r0);
  r1 = r1 > 0.f ? r1 : expm1f(r1);
  r2 = r2 > 0.f ? r2 : expm1f(r2);
  r3 = r3 > 0.f ? r3 : expm1f(r3);
  ushort4 o; o.x = f2b(r0); o.y = f2b(r1); o.z = f2b(r2); o.w = f2b(r3);
  *(ushort4*)(hout + (size_t)node * HIDD + lane * 4) = o;
}

// ---- h2 = h1 @ W2 ([N,256]x[256,32]) -> adaptive out + bf16 copy ----
__global__ __launch_bounds__(256) void gemm_h2(
    const unsigned short* __restrict__ H1, const float* __restrict__ W2f,
    void* __restrict__ Out, unsigned short* __restrict__ h2b,
    const int* __restrict__ flags, int M)
{
  const int fb = flags[0];
  __shared__ float Bs[HIDD][33];
  __shared__ float As[8][HIDD];
  int tid = threadIdx.x;
  int tx = tid & 31, ty = tid >> 5;
  int row0 = blockIdx.x * 8;
#pragma unroll
  for (int j = 0; j < 8; ++j) {            // W2 (256x32 f32) via float4
    int idx4 = tid + 256 * j;              // 2048 float4s
    float4 v = *(const float4*)(W2f + idx4 * 4);
    int k = idx4 >> 3, c = (idx4 & 7) * 4;
    Bs[k][c] = v.x; Bs[k][c + 1] = v.y; Bs[k][c + 2] = v.z; Bs[k][c + 3] = v.w;
  }
  {
    int flat = tid * 8;                    // 8 rows x 256 = 2048 bf16, 16B/thread
    int r = flat >> 8, k = flat & 255;
    int gr = row0 + r;
    if (gr < M) {
      ushort4 lo = *(const ushort4*)(H1 + (size_t)gr * HIDD + k);
      ushort4 hi = *(const ushort4*)(H1 + (size_t)gr * HIDD + k + 4);
      As[r][k] = b2f(lo.x); As[r][k + 1] = b2f(lo.y); As[r][k + 2] = b2f(lo.z); As[r][k + 3] = b2f(lo.w);
      As[r][k + 4] = b2f(hi.x); As[r][k + 5] = b2f(hi.y); As[r][k + 6] = b2f(hi.z); As[r][k + 7] = b2f(hi.w);
    } else {
#pragma unroll
      for (int q = 0; q < 8; ++q) As[r][k + q] = 0.f;
    }
  }
  __syncthreads();
  float acc = 0.f;
#pragma unroll 8
  for (int k = 0; k < HIDD; ++k) acc += As[ty][k] * Bs[k][tx];
  int row = row0 + ty;
  if (row < M) {
    size_t idx = (size_t)row * OUTD + tx;
    if (fb) ((unsigned short*)Out)[idx] = f2b(acc);
    else    ((float*)Out)[idx] = acc;
    h2b[idx] = f2b(acc);
  }
}

// ---- agg layer 2 + fused h3: wave/node; g2 = agg(h2) then
//      h3[node] = elu(g2 @ W2^T) with W2T staged in LDS ----
__global__ __launch_bounds__(256) void agg_small2(
    const unsigned short* __restrict__ h2b,
    const float* __restrict__ asrc, const float* __restrict__ adst,
    const int* __restrict__ srcP, const int* __restrict__ offs,
    const float* __restrict__ W2f,
    unsigned short* __restrict__ h3out, int N)
{
  __shared__ float W2T[32][256];   // W2T[j][c] = W2[c][j], 32 KB
  __shared__ float sg2[4][32];
  int tid = threadIdx.x;
  for (int i = tid; i < HIDD * OUTD; i += 256) {
    int c = i >> 5, j = i & 31;
    W2T[j][c] = W2f[i];
  }
  __syncthreads();
  int wid = tid >> 6, lane = tid & 63;
  int node = blockIdx.x * 4 + wid;
  if (node >= N) return;
  int grp = lane >> 4, cl = lane & 15;
  const float ad = adst[node];
  int s0 = offs[node], s1 = offs[node + 1];
  float a0 = 0.f, a1 = 0.f, den = 0.f;
  for (int e = s0 + grp; e < s1; e += 4) {
    int   sv = srcP[e];          // uniform across the 16-lane group (broadcast)
    float wv = edgew(asrc[sv] + ad);
    den += wv;
    ushort2 u = *(const ushort2*)(h2b + (size_t)sv * OUTD + cl * 2);
    a0 += wv * b2f(u.x);
    a1 += wv * b2f(u.y);
  }
  a0 += __shfl_xor(a0, 16); a0 += __shfl_xor(a0, 32);
  a1 += __shfl_xor(a1, 16); a1 += __shfl_xor(a1, 32);
  den += __shfl_xor(den, 16); den += __shfl_xor(den, 32);
  if (grp == 0) {
    float inv = 1.f / (den + 1e-16f);
    sg2[wid][cl * 2] = a0 * inv;
    sg2[wid][cl * 2 + 1] = a1 * inv;
  }
  asm volatile("s_waitcnt lgkmcnt(0)" ::: "memory");   // wave-local LDS RAW fence
  // h3 row: each lane computes cols [lane*4, lane*4+4)
  float o0 = 0.f, o1 = 0.f, o2 = 0.f, o3 = 0.f;
#pragma unroll 8
  for (int j = 0; j < 32; ++j) {
    float g = sg2[wid][j];                       // wave-uniform broadcast
    float4 wv = *(const float4*)(&W2T[j][lane * 4]);
    o0 += g * wv.x; o1 += g * wv.y; o2 += g * wv.z; o3 += g * wv.w;
  }
  o0 = o0 > 0.f ? o0 : expm1f(o0);
  o1 = o1 > 0.f ? o1 : expm1f(o1);
  o2 = o2 > 0.f ? o2 : expm1f(o2);
  o3 = o3 > 0.f ? o3 : expm1f(o3);
  ushort4 o; o.x = f2b(o0); o.y = f2b(o1); o.z = f2b(o2); o.w = f2b(o3);
  *(ushort4*)(h3out + (size_t)node * HIDD + lane * 4) = o;
}

extern "C" void kernel_launch(void* const* d_in, const int* in_sizes, int n_in,
                              void* d_out, int out_size, void* d_ws, size_t ws_size,
                              hipStream_t stream)
{
  const void*         feat = d_in[0];
  const unsigned int* eidx = (const unsigned int*)d_in[1];
  const void*         W1   = d_in[2];
  const void*         W2   = d_in[3];
  const void*         aS   = d_in[4];
  const void*         aD   = d_in[5];

  const int N = in_sizes[0] / INDIM;
  const int E = in_sizes[1] / 2;
  const int M_pad = ((N + 127) / 128) * 128;
  const int nslab = (N + SLABN - 1) / SLABN;   // 196 for N=100000; must be <= 256
  const int npb = (E + PCH - 1) / PCH;

  char* w = (char*)d_ws;
  auto alloc = [&](size_t bytes) -> char* {
    char* p = w; w += (bytes + 255) & ~(size_t)255; return p;
  };
  unsigned short* H     = (unsigned short*)alloc((size_t)M_pad * HIDD * 2);  // h1 / h3
  unsigned short* P     = (unsigned short*)alloc((size_t)M_pad * HIDD * 2);  // xp1
  unsigned short* h2b   = (unsigned short*)alloc((size_t)N * OUTD * 2);      // h2 bf16
  float* asrc = (float*)alloc((size_t)N * 4);
  float* adst = (float*)alloc((size_t)N * 4);
  int*   srcP = (int*)alloc((size_t)E * 4);     // CSR-ordered edge src
  uint2* part = (uint2*)alloc((size_t)E * 8);   // slab-partitioned (src,dst)
  int*   offs = (int*)alloc((size_t)(N + 1) * 4);
  int*   bcnt = (int*)alloc((size_t)npb * 256 * 4);
  int*   slabOff = (int*)alloc(257 * 4);
  unsigned short* W1b   = (unsigned short*)alloc((size_t)INDIM * HIDD * 2); // [512][256]
  unsigned short* W1tb  = (unsigned short*)alloc((size_t)INDIM * HIDD * 2); // [256][512]
  float* W2f  = (float*)alloc((size_t)HIDD * OUTD * 4);
  float* atS  = (float*)alloc((size_t)HIDD * 4);
  float* atD  = (float*)alloc((size_t)HIDD * 4);
  int*   flags = (int*)alloc(64);

  probe_kernel<<<1, 256, 0, stream>>>((const unsigned int*)feat, eidx, flags);

  // CSR build: radix by dst-slab (512-node slabs), slab-local CSR in LDS
  cnt_kernel<<<npb, 256, 0, stream>>>(eidx, bcnt, E, flags);
  bscan_kernel<<<1, 256, 0, stream>>>(bcnt, slabOff, npb);
  scat_kernel<<<npb, 256, 0, stream>>>(eidx, bcnt, slabOff, part, E, flags);
  slabcsr_kernel<<<nslab, 256, 0, stream>>>(part, slabOff, offs, srcP, N, nslab);

  prep_weights<<<512, 256, 0, stream>>>(W1, W2, aS, aD, W1b, W1tb, W2f, atS, atD, flags);

  const int mb = (N + 127) / 128;

  // xp1 = feat @ W1 (+ fused rowdots: asrc/adst from f32 accumulators)
  gemm_nt2<1, 0, 0, 1><<<dim3(1, mb), 512, 0, stream>>>(
      feat, W1tb, P, nullptr, 0, atS, atD, asrc, adst, flags, N, HIDD, INDIM);

  // GAT layer 1: h1 = elu(agg(xp1)/denom)
  agg_elu2<<<(N + 3) / 4, 256, 0, stream>>>(P, asrc, adst, srcP, offs, H, N);

  // h2 = h1 @ W2 -> output 0 (+ bf16 copy for layer-2 agg)
  gemm_h2<<<(N + 7) / 8, 256, 0, stream>>>(H, W2f, d_out, h2b, flags, N);

  // GAT layer 2 commuted + fused h3: h3 = elu(agg(h2) @ W2^T)
  agg_small2<<<(N + 3) / 4, 256, 0, stream>>>(h2b, asrc, adst, srcP, offs, W2f, H, N);

  // h4 = h3 @ W1^T -> output 1 (adaptive)
  gemm_nt2<0, 1, 0, 0><<<dim3(2, mb), 512, 0, stream>>>(
      H, W1b, nullptr, d_out, (size_t)N * OUTD, nullptr, nullptr, nullptr, nullptr,
      flags, N, INDIM, HIDD);
}

// Round 17
// 701.479 us; speedup vs baseline: 1.2787x; 1.2787x over previous
//
#include <hip/hip_runtime.h>
#include <cstdint>
#include <cstddef>

#define INDIM 512
#define HIDD  256
#define OUTD  32
#define PCH   4096      // edges per radix block
#define SHIFT 9
#define SLABN 512       // nodes per slab; nslab <= 256

typedef __attribute__((ext_vector_type(4))) float f32x4;
typedef __attribute__((ext_vector_type(8))) short bf16x8;

// ---- bf16 <-> f32 helpers ----
static inline __device__ float b2f(unsigned short u) {
  union { float f; unsigned int i; } v; v.i = ((unsigned int)u) << 16; return v.f;
}
static inline __device__ unsigned short f2b(float f) {
  union { float f; unsigned int i; } v; v.f = f;
  unsigned int x = v.i;
  x += 0x7fffu + ((x >> 16) & 1u);   // round-to-nearest-even
  return (unsigned short)(x >> 16);
}

// edge weight: exp(sigmoid(x)) — SAME formula in both agg kernels
static inline __device__ float edgew(float x) {
  float al = 1.f / (1.f + __expf(-x));
  return __expf(al);
}

// async global->LDS, 16B per lane. LDS dest = wave-uniform base + lane*16.
static __device__ __forceinline__ void gld16(const unsigned short* g, unsigned short* l) {
  __builtin_amdgcn_global_load_lds(
      (const __attribute__((address_space(1))) void*)g,
      (__attribute__((address_space(3))) void*)l, 16, 0, 0);
}

// ---- runtime dtype probe ----
__global__ __launch_bounds__(256) void probe_kernel(
    const unsigned int* __restrict__ feat, const unsigned int* __restrict__ eidx,
    int* __restrict__ flags)
{
  int t = threadIdx.x;
  __shared__ int cnt, oddnz;
  if (t == 0) { cnt = 0; oddnz = 0; }
  __syncthreads();
  unsigned int w = feat[t];
  unsigned short lo = (unsigned short)(w & 0xFFFFu);
  int e = (lo >> 7) & 0xFF;
  int plausible = ((lo & 0x7FFF) == 0) || (e >= 0x60 && e <= 0x9F);
  atomicAdd(&cnt, plausible);
  if (t & 1) { if (eidx[t] != 0u) atomicAdd(&oddnz, 1); }
  __syncthreads();
  if (t == 0) { flags[0] = (cnt >= 192) ? 1 : 0; flags[1] = (oddnz == 0) ? 1 : 0; }
}

// ---- radix pass A: per-block slab counts (LDS hist, plain global writes) ----
__global__ __launch_bounds__(256) void cnt_kernel(
    const unsigned int* __restrict__ eidx, int* __restrict__ bcnt,
    int E, const int* __restrict__ flags)
{
  __shared__ int hist[256];
  int t = threadIdx.x;
  hist[t] = 0;
  __syncthreads();
  int e0 = blockIdx.x * PCH;
  const int i64 = flags[1];
  for (int i = t; i < PCH; i += 256) {
    int e = e0 + i; if (e >= E) break;
    int d = i64 ? (int)eidx[2 * ((size_t)E + e)] : (int)eidx[(size_t)E + e];
    atomicAdd(&hist[d >> SHIFT], 1);
  }
  __syncthreads();
  bcnt[blockIdx.x * 256 + t] = hist[t];
}

// ---- radix pass B: bcnt -> within-slab block prefixes; slabOff excl scan ----
__global__ __launch_bounds__(256) void bscan_kernel(
    int* __restrict__ bcnt, int* __restrict__ slabOff, int npb)
{
  __shared__ int wsum[4];
  int t = threadIdx.x, lane = t & 63, wv = t >> 6;
  int run = 0;
  for (int b = 0; b < npb; ++b) {
    int v = bcnt[b * 256 + t];
    bcnt[b * 256 + t] = run;     // within-slab prefix
    run += v;
  }
  int inc = run;
#pragma unroll
  for (int o = 1; o < 64; o <<= 1) {
    int u = __shfl_up(inc, o);
    if (lane >= o) inc += u;
  }
  if (lane == 63) wsum[wv] = inc;
  __syncthreads();
  if (t < 4) {
    int v = wsum[t], s = v;
#pragma unroll
    for (int o = 1; o < 4; o <<= 1) {
      int u = __shfl_up(s, o);
      if (t >= o) s += u;
    }
    wsum[t] = s - v;
  }
  __syncthreads();
  int exc = wsum[wv] + inc - run;
  slabOff[t] = exc;
  if (t == 255) slabOff[256] = exc + run;   // = E
}

// ---- radix pass C: scatter (src,dst) into slab-contiguous part[] ----
__global__ __launch_bounds__(256) void scat_kernel(
    const unsigned int* __restrict__ eidx, const int* __restrict__ bcnt,
    const int* __restrict__ slabOff, uint2* __restrict__ part,
    int E, const int* __restrict__ flags)
{
  __shared__ int cur[256];
  int t = threadIdx.x;
  cur[t] = slabOff[t] + bcnt[blockIdx.x * 256 + t];
  __syncthreads();
  int e0 = blockIdx.x * PCH;
  const int i64 = flags[1];
  for (int i = t; i < PCH; i += 256) {
    int e = e0 + i; if (e >= E) break;
    int s, d;
    if (i64) { s = (int)eidx[2 * (size_t)e]; d = (int)eidx[2 * ((size_t)E + e)]; }
    else     { s = (int)eidx[e];             d = (int)eidx[(size_t)E + e]; }
    int pos = atomicAdd(&cur[d >> SHIFT], 1);
    part[pos] = make_uint2((unsigned)s, (unsigned)d);
  }
}

// ---- radix pass D: per-slab CSR build fully in LDS (deg, scan, fill) ----
__global__ __launch_bounds__(256) void slabcsr_kernel(
    const uint2* __restrict__ part, const int* __restrict__ slabOff,
    int* __restrict__ offs, int* __restrict__ srcP, int N, int nslab)
{
  __shared__ int deg[SLABN];
  __shared__ int wsum[4];
  int sl = blockIdx.x, t = threadIdx.x;
  int n0 = sl << SHIFT;
  int nn = N - n0; if (nn > SLABN) nn = SLABN;
  int s0 = slabOff[sl], s1 = slabOff[sl + 1];
  for (int i = t; i < SLABN; i += 256) deg[i] = 0;
  __syncthreads();
  for (int i = s0 + t; i < s1; i += 256)
    atomicAdd(&deg[(int)part[i].y - n0], 1);
  __syncthreads();
  int bi = t * 2;
  int l0 = deg[bi], l1 = deg[bi + 1];
  int s = l0 + l1;
  int ws = s;
#pragma unroll
  for (int o = 1; o < 64; o <<= 1) {
    int u = __shfl_up(ws, o);
    if ((t & 63) >= o) ws += u;
  }
  if ((t & 63) == 63) wsum[t >> 6] = ws;
  __syncthreads();
  if (t < 4) {
    int v = wsum[t], inc = v;
#pragma unroll
    for (int o = 1; o < 4; o <<= 1) {
      int u = __shfl_up(inc, o);
      if (t >= o) inc += u;
    }
    wsum[t] = inc - v;
  }
  __syncthreads();
  int run = wsum[t >> 6] + (ws - s);   // thread-exclusive base
  deg[bi] = run;
  if (bi < nn) offs[n0 + bi] = s0 + run;
  run += l0;
  deg[bi + 1] = run;
  if (bi + 1 < nn) offs[n0 + bi + 1] = s0 + run;
  __syncthreads();
  for (int i = s0 + t; i < s1; i += 256) {
    uint2 p = part[i];
    int pos = s0 + atomicAdd(&deg[(int)p.y - n0], 1);
    srcP[pos] = (int)p.x;
  }
  if (sl == nslab - 1 && t == 0) offs[N] = s1;
}

static inline __device__ float ldadapt(const void* p, size_t i, int isbf) {
  return isbf ? b2f(((const unsigned short*)p)[i]) : ((const float*)p)[i];
}

// ---- weight prep: W1b, W1tb (bf16), W2f (f32), att (f32) ----
__global__ __launch_bounds__(256) void prep_weights(
    const void* __restrict__ W1, const void* __restrict__ W2,
    const void* __restrict__ aS, const void* __restrict__ aD,
    unsigned short* __restrict__ W1b, unsigned short* __restrict__ W1tb,
    float* __restrict__ W2f,
    float* __restrict__ atS, float* __restrict__ atD,
    const int* __restrict__ flags)
{
  const int fb = flags[0];
  int i = blockIdx.x * 256 + threadIdx.x;
  if (i < INDIM * HIDD) {               // W1: [512][256]
    int r = i >> 8, c = i & 255;
    float w0 = ldadapt(W1, i, fb);
    unsigned short wb = f2b(w0);
    W1b[i] = wb;                        // Bt for h4: [512 rows][256 k]
    W1tb[c * INDIM + r] = wb;           // Bt for xp1: [256 rows][512 k]
  }
  if (i < HIDD * OUTD) W2f[i] = ldadapt(W2, i, fb);
  if (i < HIDD) { atS[i] = ldadapt(aS, i, fb); atD[i] = ldadapt(aD, i, fb); }
}

// =====================================================================
// MFMA NT GEMM, BM=128 x BN=256, BK=64, 512 threads = 8 waves (2x4 of
// 64x64). T2 swizzle (rule #21 form). Single-buffered (r14 dbuf neutral).
// AMODE:   0 = A bf16 ws buffer; 1 = A external: fb ? bf16 : f32 reg-staged
// OUTMODE: 0 = bf16 to Cb; 1 = adaptive (flags[0]) to Out+outOff
// EPI:     0 = none; 1 = ELU before store
// DOTS:    1 = also emit asrc/adst row-dots vs atS/atD (requires grid.x==1)
// =====================================================================
template<int AMODE, int OUTMODE, int EPI, int DOTS>
__global__ __launch_bounds__(512, 4) void gemm_nt2(
    const void* __restrict__ Av, const unsigned short* __restrict__ Bt,
    unsigned short* __restrict__ Cb, void* __restrict__ Out, size_t outOff,
    const float* __restrict__ atS, const float* __restrict__ atD,
    float* __restrict__ asrc, float* __restrict__ adst,
    const int* __restrict__ flags, int M, int Nn, int K)
{
  __shared__ unsigned short Als[128 * 64];   // 16 KB
  __shared__ unsigned short Bls[256 * 64];   // 32 KB
  __shared__ float sdot[2][128];             // 1 KB (DOTS only)
  const int tid = threadIdx.x, lane = tid & 63, wid = tid >> 6;   // 8 waves
  const int wr = wid >> 2, wc = wid & 3;     // 2x4 wave grid, 64x64 each
  const int rowBase = blockIdx.y * 128, colBase = blockIdx.x * 256;
  const int fb = flags[0];

  const int srow = (lane >> 3), sg = lane & 7;
  const int sgx = sg ^ srow;                 // inverse-swizzled source granule

  f32x4 acc[4][4] = {};

  for (int kt = 0; kt < K; kt += 64) {
    // ---- stage A: 16 chunks (1KB = 8 rows), 2 per wave ----
    if (AMODE == 1 && !fb) {
      const float* Af = (const float*)Av;
#pragma unroll
      for (int i = 0; i < 2; ++i) {
        int row = wid * 16 + i * 8 + srow;
        int gr = rowBase + row; if (gr > M - 1) gr = M - 1;
        const float* sp = Af + (size_t)gr * K + kt + sg * 8;   // linear coalesced
        float4 lo = *(const float4*)sp;
        float4 hi = *(const float4*)(sp + 4);
        union { unsigned short us[8]; int4 v; } cv;
        cv.us[0] = f2b(lo.x); cv.us[1] = f2b(lo.y); cv.us[2] = f2b(lo.z); cv.us[3] = f2b(lo.w);
        cv.us[4] = f2b(hi.x); cv.us[5] = f2b(hi.y); cv.us[6] = f2b(hi.z); cv.us[7] = f2b(hi.w);
        *(int4*)(Als + row * 64 + (sgx << 3)) = cv.v;          // swizzled ds_write
      }
    } else {
      const unsigned short* Ab = (const unsigned short*)Av;
#pragma unroll
      for (int i = 0; i < 2; ++i) {
        int row = wid * 16 + i * 8 + srow;
        int gr = rowBase + row;
        if (AMODE == 1 && gr > M - 1) gr = M - 1;   // external input: clamp
        gld16(Ab + (size_t)gr * K + kt + (sgx << 3), Als + (wid * 2 + i) * 512);
      }
    }
    // ---- stage B: 32 chunks, 4 per wave ----
#pragma unroll
    for (int i = 0; i < 4; ++i) {
      int row = wid * 32 + i * 8 + srow;
      gld16(Bt + (size_t)(colBase + row) * K + kt + (sgx << 3), Bls + (wid * 4 + i) * 512);
    }
    __syncthreads();

    bf16x8 af[4], bfr[4];
#pragma unroll
    for (int ks = 0; ks < 2; ++ks) {
      int gl = ks * 4 + (lane >> 4);
      int gx = gl ^ (lane & 7);        // row&7 == lane&7 for fragment rows
#pragma unroll
      for (int mi = 0; mi < 4; ++mi) {
        int row = wr * 64 + mi * 16 + (lane & 15);
        af[mi] = *(const bf16x8*)(Als + row * 64 + (gx << 3));
      }
#pragma unroll
      for (int ni = 0; ni < 4; ++ni) {
        int row = wc * 64 + ni * 16 + (lane & 15);
        bfr[ni] = *(const bf16x8*)(Bls + row * 64 + (gx << 3));
      }
#pragma unroll
      for (int mi = 0; mi < 4; ++mi)
#pragma unroll
        for (int ni = 0; ni < 4; ++ni)
          acc[mi][ni] = __builtin_amdgcn_mfma_f32_16x16x32_bf16(af[mi], bfr[ni], acc[mi][ni], 0, 0, 0);
    }
    __syncthreads();
  }

  // C/D: col = lane&15, row = (lane>>4)*4 + reg
#pragma unroll
  for (int mi = 0; mi < 4; ++mi) {
    int r0 = rowBase + wr * 64 + mi * 16 + (lane >> 4) * 4;
#pragma unroll
    for (int ni = 0; ni < 4; ++ni) {
      int c = colBase + wc * 64 + ni * 16 + (lane & 15);
#pragma unroll
      for (int v = 0; v < 4; ++v) {
        int r = r0 + v;
        if (r < M) {
          size_t idx = (size_t)r * Nn + c;
          float x = acc[mi][ni][v];
          if (EPI) x = x > 0.f ? x : expm1f(x);
          if (OUTMODE == 0) Cb[idx] = f2b(x);
          else {
            if (fb) ((unsigned short*)Out)[outOff + idx] = f2b(x);
            else    ((float*)Out)[outOff + idx] = x;
          }
        }
      }
    }
  }

  // ---- fused rowdots epilogue (xp1 only): asrc/adst from f32 accumulators ----
  if (DOTS) {
    if (tid < 128) { sdot[0][tid] = 0.f; sdot[1][tid] = 0.f; }
    __syncthreads();
    float vS[4], vD[4];
#pragma unroll
    for (int ni = 0; ni < 4; ++ni) {
      int c = colBase + wc * 64 + ni * 16 + (lane & 15);
      vS[ni] = atS[c]; vD[ni] = atD[c];
    }
#pragma unroll
    for (int mi = 0; mi < 4; ++mi) {
#pragma unroll
      for (int v = 0; v < 4; ++v) {
        float ps = 0.f, pd = 0.f;
#pragma unroll
        for (int ni = 0; ni < 4; ++ni) {
          ps += acc[mi][ni][v] * vS[ni];
          pd += acc[mi][ni][v] * vD[ni];
        }
#pragma unroll
        for (int off = 1; off < 16; off <<= 1) {
          ps += __shfl_xor(ps, off);
          pd += __shfl_xor(pd, off);
        }
        if ((lane & 15) == 0) {
          int rl = wr * 64 + mi * 16 + (lane >> 4) * 4 + v;
          atomicAdd(&sdot[0][rl], ps);   // combine the 4 column-waves
          atomicAdd(&sdot[1][rl], pd);
        }
      }
    }
    __syncthreads();
    if (tid < 128) {
      int r = rowBase + tid;
      if (r < M) { asrc[r] = sdot[0][tid]; adst[r] = sdot[1][tid]; }
    }
  }
}

// ---- agg layer 1: wave/node, 16 gathers in flight, denominator in-loop ----
__global__ __launch_bounds__(256) void agg_elu2(
    const unsigned short* __restrict__ xp,
    const float* __restrict__ asrc, const float* __restrict__ adst,
    const int* __restrict__ srcP, const int* __restrict__ offs,
    unsigned short* __restrict__ hout, int N)
{
  __shared__ int   sS[4][64];
  __shared__ float sW[4][64];
  int wid = threadIdx.x >> 6, lane = threadIdx.x & 63;
  int node = blockIdx.x * 4 + wid;
  if (node >= N) return;
  const float ad = adst[node];
  int s0 = offs[node], s1 = offs[node + 1];
  float a0 = 0.f, a1 = 0.f, a2 = 0.f, a3 = 0.f, den = 0.f;
  for (int base = s0; base < s1; base += 64) {
    int cnt = s1 - base; if (cnt > 64) cnt = 64;
    if (lane < cnt) {
      int sv = srcP[base + lane];
      sS[wid][lane] = sv;
      sW[wid][lane] = edgew(asrc[sv] + ad);
    }
    asm volatile("s_waitcnt lgkmcnt(0)" ::: "memory");   // wave-local LDS RAW fence
    int j = 0;
    for (; j + 16 <= cnt; j += 16) {          // 16 gathers in flight
      ushort4 u[16];
#pragma unroll
      for (int q = 0; q < 16; ++q)
        u[q] = *(const ushort4*)(xp + (size_t)sS[wid][j + q] * HIDD + lane * 4);
#pragma unroll
      for (int q = 0; q < 16; ++q) {
        float wv = sW[wid][j + q];
        den += wv;
        a0 += wv * b2f(u[q].x); a1 += wv * b2f(u[q].y);
        a2 += wv * b2f(u[q].z); a3 += wv * b2f(u[q].w);
      }
    }
    for (; j + 8 <= cnt; j += 8) {
      ushort4 u[8];
#pragma unroll
      for (int q = 0; q < 8; ++q)
        u[q] = *(const ushort4*)(xp + (size_t)sS[wid][j + q] * HIDD + lane * 4);
#pragma unroll
      for (int q = 0; q < 8; ++q) {
        float wv = sW[wid][j + q];
        den += wv;
        a0 += wv * b2f(u[q].x); a1 += wv * b2f(u[q].y);
        a2 += wv * b2f(u[q].z); a3 += wv * b2f(u[q].w);
      }
    }
    for (; j < cnt; ++j) {
      int   sv = sS[wid][j];
      float wv = sW[wid][j];
      den += wv;
      ushort4 u = *(const ushort4*)(xp + (size_t)sv * HIDD + lane * 4);
      a0 += wv * b2f(u.x); a1 += wv * b2f(u.y); a2 += wv * b2f(u.z); a3 += wv * b2f(u.w);
    }
  }
  float inv = 1.f / (den + 1e-16f);
  float r0 = a0 * inv, r1 = a1 * inv, r2 = a2 * inv, r3 = a3 * inv;
  r0 = r0 > 0.f ? r0 : expm1f(r0);
  r1 = r1 > 0.f ? r1 : expm1f(r1);
  r2 = r2 > 0.f ? r2 : expm1f(r2);
  r3 = r3 > 0.f ? r3 : expm1f(r3);
  ushort4 o; o.x = f2b(r0); o.y = f2b(r1); o.z = f2b(r2); o.w = f2b(r3);
  *(ushort4*)(hout + (size_t)node * HIDD + lane * 4) = o;
}

// ---- h2 = h1 @ W2 ([N,256]x[256,32]) -> adaptive out + bf16 copy ----
__global__ __launch_bounds__(256) void gemm_h2(
    const unsigned short* __restrict__ H1, const float* __restrict__ W2f,
    void* __restrict__ Out, unsigned short* __restrict__ h2b,
    const int* __restrict__ flags, int M)
{
  const int fb = flags[0];
  __shared__ float Bs[HIDD][33];
  __shared__ float As[8][HIDD];
  int tid = threadIdx.x;
  int tx = tid & 31, ty = tid >> 5;
  int row0 = blockIdx.x * 8;
#pragma unroll
  for (int j = 0; j < 8; ++j) {            // W2 (256x32 f32) via float4
    int idx4 = tid + 256 * j;              // 2048 float4s
    float4 v = *(const float4*)(W2f + idx4 * 4);
    int k = idx4 >> 3, c = (idx4 & 7) * 4;
    Bs[k][c] = v.x; Bs[k][c + 1] = v.y; Bs[k][c + 2] = v.z; Bs[k][c + 3] = v.w;
  }
  {
    int flat = tid * 8;                    // 8 rows x 256 = 2048 bf16, 16B/thread
    int r = flat >> 8, k = flat & 255;
    int gr = row0 + r;
    if (gr < M) {
      ushort4 lo = *(const ushort4*)(H1 + (size_t)gr * HIDD + k);
      ushort4 hi = *(const ushort4*)(H1 + (size_t)gr * HIDD + k + 4);
      As[r][k] = b2f(lo.x); As[r][k + 1] = b2f(lo.y); As[r][k + 2] = b2f(lo.z); As[r][k + 3] = b2f(lo.w);
      As[r][k + 4] = b2f(hi.x); As[r][k + 5] = b2f(hi.y); As[r][k + 6] = b2f(hi.z); As[r][k + 7] = b2f(hi.w);
    } else {
#pragma unroll
      for (int q = 0; q < 8; ++q) As[r][k + q] = 0.f;
    }
  }
  __syncthreads();
  float acc = 0.f;
#pragma unroll 8
  for (int k = 0; k < HIDD; ++k) acc += As[ty][k] * Bs[k][tx];
  int row = row0 + ty;
  if (row < M) {
    size_t idx = (size_t)row * OUTD + tx;
    if (fb) ((unsigned short*)Out)[idx] = f2b(acc);
    else    ((float*)Out)[idx] = acc;
    h2b[idx] = f2b(acc);
  }
}

// ---- agg layer 2 + fused h3, bank-bijective W2T layout:
//      W2T element (j,c) stored at [j*256 + (c^j)] -> conflict-free writes
//      (coalesced loads, lanes span j) AND conflict-free scalar reads
//      (fixed j, lanes span c). Lane l computes cols {l, l+64, l+128, l+192}. ----
__global__ __launch_bounds__(256) void agg_small2(
    const unsigned short* __restrict__ h2b,
    const float* __restrict__ asrc, const float* __restrict__ adst,
    const int* __restrict__ srcP, const int* __restrict__ offs,
    const float* __restrict__ W2f,
    unsigned short* __restrict__ h3out, int N)
{
  __shared__ float W2T[32 * 256];  // swizzled [j][c^j], 32 KB
  __shared__ float sg2[4][32];
  int tid = threadIdx.x;
#pragma unroll
  for (int k = 0; k < 32; ++k) {   // coalesced W2f read; bank-bijective write
    int i = tid + 256 * k;
    int c = i >> 5, j = i & 31;
    W2T[j * 256 + (c ^ j)] = W2f[i];
  }
  __syncthreads();
  int wid = tid >> 6, lane = tid & 63;
  int node = blockIdx.x * 4 + wid;
  if (node >= N) return;
  int grp = lane >> 4, cl = lane & 15;
  const float ad = adst[node];
  int s0 = offs[node], s1 = offs[node + 1];
  float a0 = 0.f, a1 = 0.f, den = 0.f;
  for (int e = s0 + grp; e < s1; e += 4) {
    int   sv = srcP[e];          // uniform across the 16-lane group (broadcast)
    float wv = edgew(asrc[sv] + ad);
    den += wv;
    ushort2 u = *(const ushort2*)(h2b + (size_t)sv * OUTD + cl * 2);
    a0 += wv * b2f(u.x);
    a1 += wv * b2f(u.y);
  }
  a0 += __shfl_xor(a0, 16); a0 += __shfl_xor(a0, 32);
  a1 += __shfl_xor(a1, 16); a1 += __shfl_xor(a1, 32);
  den += __shfl_xor(den, 16); den += __shfl_xor(den, 32);
  if (grp == 0) {
    float inv = 1.f / (den + 1e-16f);
    sg2[wid][cl * 2] = a0 * inv;
    sg2[wid][cl * 2 + 1] = a1 * inv;
  }
  asm volatile("s_waitcnt lgkmcnt(0)" ::: "memory");   // wave-local LDS RAW fence
  // h3 row: lane computes cols {lane + q*64}; scalar reads, bank-bijective
  float o0 = 0.f, o1 = 0.f, o2 = 0.f, o3 = 0.f;
#pragma unroll 4
  for (int j = 0; j < 32; ++j) {
    float g = sg2[wid][j];                       // wave-uniform broadcast
    o0 += g * W2T[j * 256 + ((lane)       ^ j)];
    o1 += g * W2T[j * 256 + ((lane + 64)  ^ j)];
    o2 += g * W2T[j * 256 + ((lane + 128) ^ j)];
    o3 += g * W2T[j * 256 + ((lane + 192) ^ j)];
  }
  o0 = o0 > 0.f ? o0 : expm1f(o0);
  o1 = o1 > 0.f ? o1 : expm1f(o1);
  o2 = o2 > 0.f ? o2 : expm1f(o2);
  o3 = o3 > 0.f ? o3 : expm1f(o3);
  unsigned short* hb = h3out + (size_t)node * HIDD;
  hb[lane]       = f2b(o0);
  hb[lane + 64]  = f2b(o1);
  hb[lane + 128] = f2b(o2);
  hb[lane + 192] = f2b(o3);
}

extern "C" void kernel_launch(void* const* d_in, const int* in_sizes, int n_in,
                              void* d_out, int out_size, void* d_ws, size_t ws_size,
                              hipStream_t stream)
{
  const void*         feat = d_in[0];
  const unsigned int* eidx = (const unsigned int*)d_in[1];
  const void*         W1   = d_in[2];
  const void*         W2   = d_in[3];
  const void*         aS   = d_in[4];
  const void*         aD   = d_in[5];

  const int N = in_sizes[0] / INDIM;
  const int E = in_sizes[1] / 2;
  const int M_pad = ((N + 127) / 128) * 128;
  const int nslab = (N + SLABN - 1) / SLABN;   // 196 for N=100000; must be <= 256
  const int npb = (E + PCH - 1) / PCH;

  char* w = (char*)d_ws;
  auto alloc = [&](size_t bytes) -> char* {
    char* p = w; w += (bytes + 255) & ~(size_t)255; return p;
  };
  unsigned short* H     = (unsigned short*)alloc((size_t)M_pad * HIDD * 2);  // h1 / h3
  unsigned short* P     = (unsigned short*)alloc((size_t)M_pad * HIDD * 2);  // xp1
  unsigned short* h2b   = (unsigned short*)alloc((size_t)N * OUTD * 2);      // h2 bf16
  float* asrc = (float*)alloc((size_t)N * 4);
  float* adst = (float*)alloc((size_t)N * 4);
  int*   srcP = (int*)alloc((size_t)E * 4);     // CSR-ordered edge src
  uint2* part = (uint2*)alloc((size_t)E * 8);   // slab-partitioned (src,dst)
  int*   offs = (int*)alloc((size_t)(N + 1) * 4);
  int*   bcnt = (int*)alloc((size_t)npb * 256 * 4);
  int*   slabOff = (int*)alloc(257 * 4);
  unsigned short* W1b   = (unsigned short*)alloc((size_t)INDIM * HIDD * 2); // [512][256]
  unsigned short* W1tb  = (unsigned short*)alloc((size_t)INDIM * HIDD * 2); // [256][512]
  float* W2f  = (float*)alloc((size_t)HIDD * OUTD * 4);
  float* atS  = (float*)alloc((size_t)HIDD * 4);
  float* atD  = (float*)alloc((size_t)HIDD * 4);
  int*   flags = (int*)alloc(64);

  probe_kernel<<<1, 256, 0, stream>>>((const unsigned int*)feat, eidx, flags);

  // CSR build: radix by dst-slab (512-node slabs), slab-local CSR in LDS
  cnt_kernel<<<npb, 256, 0, stream>>>(eidx, bcnt, E, flags);
  bscan_kernel<<<1, 256, 0, stream>>>(bcnt, slabOff, npb);
  scat_kernel<<<npb, 256, 0, stream>>>(eidx, bcnt, slabOff, part, E, flags);
  slabcsr_kernel<<<nslab, 256, 0, stream>>>(part, slabOff, offs, srcP, N, nslab);

  prep_weights<<<512, 256, 0, stream>>>(W1, W2, aS, aD, W1b, W1tb, W2f, atS, atD, flags);

  const int mb = (N + 127) / 128;

  // xp1 = feat @ W1 (+ fused rowdots: asrc/adst from f32 accumulators)
  gemm_nt2<1, 0, 0, 1><<<dim3(1, mb), 512, 0, stream>>>(
      feat, W1tb, P, nullptr, 0, atS, atD, asrc, adst, flags, N, HIDD, INDIM);

  // GAT layer 1: h1 = elu(agg(xp1)/denom)
  agg_elu2<<<(N + 3) / 4, 256, 0, stream>>>(P, asrc, adst, srcP, offs, H, N);

  // h2 = h1 @ W2 -> output 0 (+ bf16 copy for layer-2 agg)
  gemm_h2<<<(N + 7) / 8, 256, 0, stream>>>(H, W2f, d_out, h2b, flags, N);

  // GAT layer 2 commuted + fused h3: h3 = elu(agg(h2) @ W2^T)
  agg_small2<<<(N + 3) / 4, 256, 0, stream>>>(h2b, asrc, adst, srcP, offs, W2f, H, N);

  // h4 = h3 @ W1^T -> output 1 (adaptive)
  gemm_nt2<0, 1, 0, 0><<<dim3(2, mb), 512, 0, stream>>>(
      H, W1b, nullptr, d_out, (size_t)N * OUTD, nullptr, nullptr, nullptr, nullptr,
      flags, N, INDIM, HIDD);
}

// Round 18
// 604.663 us; speedup vs baseline: 1.4834x; 1.1601x over previous
//
#include <hip/hip_runtime.h>
#include <cstdint>
#include <cstddef>

#define INDIM 512
#define HIDD  256
#define OUTD  32
#define PCH   4096      // edges per radix block
#define SHIFT 9
#define SLABN 512       // nodes per slab; nslab <= 256

typedef __attribute__((ext_vector_type(4))) float f32x4;
typedef __attribute__((ext_vector_type(8))) short bf16x8;

// ---- bf16 <-> f32 helpers ----
static inline __device__ float b2f(unsigned short u) {
  union { float f; unsigned int i; } v; v.i = ((unsigned int)u) << 16; return v.f;
}
static inline __device__ unsigned short f2b(float f) {
  union { float f; unsigned int i; } v; v.f = f;
  unsigned int x = v.i;
  x += 0x7fffu + ((x >> 16) & 1u);   // round-to-nearest-even
  return (unsigned short)(x >> 16);
}

// edge weight: exp(sigmoid(x)) — SAME formula in both agg kernels
static inline __device__ float edgew(float x) {
  float al = 1.f / (1.f + __expf(-x));
  return __expf(al);
}

// async global->LDS, 16B per lane. LDS dest = wave-uniform base + lane*16.
static __device__ __forceinline__ void gld16(const unsigned short* g, unsigned short* l) {
  __builtin_amdgcn_global_load_lds(
      (const __attribute__((address_space(1))) void*)g,
      (__attribute__((address_space(3))) void*)l, 16, 0, 0);
}

// ---- runtime dtype probe ----
__global__ __launch_bounds__(256) void probe_kernel(
    const unsigned int* __restrict__ feat, const unsigned int* __restrict__ eidx,
    int* __restrict__ flags)
{
  int t = threadIdx.x;
  __shared__ int cnt, oddnz;
  if (t == 0) { cnt = 0; oddnz = 0; }
  __syncthreads();
  unsigned int w = feat[t];
  unsigned short lo = (unsigned short)(w & 0xFFFFu);
  int e = (lo >> 7) & 0xFF;
  int plausible = ((lo & 0x7FFF) == 0) || (e >= 0x60 && e <= 0x9F);
  atomicAdd(&cnt, plausible);
  if (t & 1) { if (eidx[t] != 0u) atomicAdd(&oddnz, 1); }
  __syncthreads();
  if (t == 0) { flags[0] = (cnt >= 192) ? 1 : 0; flags[1] = (oddnz == 0) ? 1 : 0; }
}

// ---- radix pass A: per-block slab counts (LDS hist, plain global writes) ----
__global__ __launch_bounds__(256) void cnt_kernel(
    const unsigned int* __restrict__ eidx, int* __restrict__ bcnt,
    int E, const int* __restrict__ flags)
{
  __shared__ int hist[256];
  int t = threadIdx.x;
  hist[t] = 0;
  __syncthreads();
  int e0 = blockIdx.x * PCH;
  const int i64 = flags[1];
  for (int i = t; i < PCH; i += 256) {
    int e = e0 + i; if (e >= E) break;
    int d = i64 ? (int)eidx[2 * ((size_t)E + e)] : (int)eidx[(size_t)E + e];
    atomicAdd(&hist[d >> SHIFT], 1);
  }
  __syncthreads();
  bcnt[blockIdx.x * 256 + t] = hist[t];
}

// ---- radix pass B: bcnt -> within-slab block prefixes; slabOff excl scan ----
__global__ __launch_bounds__(256) void bscan_kernel(
    int* __restrict__ bcnt, int* __restrict__ slabOff, int npb)
{
  __shared__ int wsum[4];
  int t = threadIdx.x, lane = t & 63, wv = t >> 6;
  int run = 0;
  for (int b = 0; b < npb; ++b) {
    int v = bcnt[b * 256 + t];
    bcnt[b * 256 + t] = run;     // within-slab prefix
    run += v;
  }
  int inc = run;
#pragma unroll
  for (int o = 1; o < 64; o <<= 1) {
    int u = __shfl_up(inc, o);
    if (lane >= o) inc += u;
  }
  if (lane == 63) wsum[wv] = inc;
  __syncthreads();
  if (t < 4) {
    int v = wsum[t], s = v;
#pragma unroll
    for (int o = 1; o < 4; o <<= 1) {
      int u = __shfl_up(s, o);
      if (t >= o) s += u;
    }
    wsum[t] = s - v;
  }
  __syncthreads();
  int exc = wsum[wv] + inc - run;
  slabOff[t] = exc;
  if (t == 255) slabOff[256] = exc + run;   // = E
}

// ---- radix pass C: scatter (src,dst) into slab-contiguous part[] ----
__global__ __launch_bounds__(256) void scat_kernel(
    const unsigned int* __restrict__ eidx, const int* __restrict__ bcnt,
    const int* __restrict__ slabOff, uint2* __restrict__ part,
    int E, const int* __restrict__ flags)
{
  __shared__ int cur[256];
  int t = threadIdx.x;
  cur[t] = slabOff[t] + bcnt[blockIdx.x * 256 + t];
  __syncthreads();
  int e0 = blockIdx.x * PCH;
  const int i64 = flags[1];
  for (int i = t; i < PCH; i += 256) {
    int e = e0 + i; if (e >= E) break;
    int s, d;
    if (i64) { s = (int)eidx[2 * (size_t)e]; d = (int)eidx[2 * ((size_t)E + e)]; }
    else     { s = (int)eidx[e];             d = (int)eidx[(size_t)E + e]; }
    int pos = atomicAdd(&cur[d >> SHIFT], 1);
    part[pos] = make_uint2((unsigned)s, (unsigned)d);
  }
}

// ---- radix pass D: per-slab CSR build fully in LDS (deg, scan, fill) ----
__global__ __launch_bounds__(256) void slabcsr_kernel(
    const uint2* __restrict__ part, const int* __restrict__ slabOff,
    int* __restrict__ offs, int* __restrict__ srcP, int N, int nslab)
{
  __shared__ int deg[SLABN];
  __shared__ int wsum[4];
  int sl = blockIdx.x, t = threadIdx.x;
  int n0 = sl << SHIFT;
  int nn = N - n0; if (nn > SLABN) nn = SLABN;
  int s0 = slabOff[sl], s1 = slabOff[sl + 1];
  for (int i = t; i < SLABN; i += 256) deg[i] = 0;
  __syncthreads();
  for (int i = s0 + t; i < s1; i += 256)
    atomicAdd(&deg[(int)part[i].y - n0], 1);
  __syncthreads();
  int bi = t * 2;
  int l0 = deg[bi], l1 = deg[bi + 1];
  int s = l0 + l1;
  int ws = s;
#pragma unroll
  for (int o = 1; o < 64; o <<= 1) {
    int u = __shfl_up(ws, o);
    if ((t & 63) >= o) ws += u;
  }
  if ((t & 63) == 63) wsum[t >> 6] = ws;
  __syncthreads();
  if (t < 4) {
    int v = wsum[t], inc = v;
#pragma unroll
    for (int o = 1; o < 4; o <<= 1) {
      int u = __shfl_up(inc, o);
      if (t >= o) inc += u;
    }
    wsum[t] = inc - v;
  }
  __syncthreads();
  int run = wsum[t >> 6] + (ws - s);   // thread-exclusive base
  deg[bi] = run;
  if (bi < nn) offs[n0 + bi] = s0 + run;
  run += l0;
  deg[bi + 1] = run;
  if (bi + 1 < nn) offs[n0 + bi + 1] = s0 + run;
  __syncthreads();
  for (int i = s0 + t; i < s1; i += 256) {
    uint2 p = part[i];
    int pos = s0 + atomicAdd(&deg[(int)p.y - n0], 1);
    srcP[pos] = (int)p.x;
  }
  if (sl == nslab - 1 && t == 0) offs[N] = s1;
}

static inline __device__ float ldadapt(const void* p, size_t i, int isbf) {
  return isbf ? b2f(((const unsigned short*)p)[i]) : ((const float*)p)[i];
}

// ---- weight prep: W1b, W1tb (bf16), W2f (f32), W2b64 ([256][64] bf16 K-pad), att ----
__global__ __launch_bounds__(256) void prep_weights(
    const void* __restrict__ W1, const void* __restrict__ W2,
    const void* __restrict__ aS, const void* __restrict__ aD,
    unsigned short* __restrict__ W1b, unsigned short* __restrict__ W1tb,
    float* __restrict__ W2f, unsigned short* __restrict__ W2b64,
    float* __restrict__ atS, float* __restrict__ atD,
    const int* __restrict__ flags)
{
  const int fb = flags[0];
  int i = blockIdx.x * 256 + threadIdx.x;
  if (i < INDIM * HIDD) {               // W1: [512][256]
    int r = i >> 8, c = i & 255;
    float w0 = ldadapt(W1, i, fb);
    unsigned short wb = f2b(w0);
    W1b[i] = wb;                        // Bt for h4: [512 rows][256 k]
    W1tb[c * INDIM + r] = wb;           // Bt for xp1: [256 rows][512 k]
  }
  if (i < HIDD * OUTD) {                // W2: [256][32]
    int r = i >> 5, c = i & 31;
    float w0 = ldadapt(W2, i, fb);
    W2f[i] = w0;
    W2b64[r * 64 + c] = f2b(w0);        // Bt for h3: [256 rows][64 k], upper 32 zero
    W2b64[r * 64 + 32 + c] = 0;
  }
  if (i < HIDD) { atS[i] = ldadapt(aS, i, fb); atD[i] = ldadapt(aD, i, fb); }
}

// =====================================================================
// MFMA NT GEMM, BM=128 x BN=256, BK=64, 512 threads = 8 waves (2x4 of
// 64x64). T2 swizzle (rule #21 form). Single-buffered (r14 dbuf neutral).
// AMODE:   0 = A bf16 ws buffer; 1 = A external: fb ? bf16 : f32 reg-staged
// OUTMODE: 0 = bf16 to Cb; 1 = adaptive (flags[0]) to Out+outOff
// EPI:     0 = none; 1 = ELU before store
// DOTS:    1 = also emit asrc/adst row-dots vs atS/atD (requires grid.x==1)
// =====================================================================
template<int AMODE, int OUTMODE, int EPI, int DOTS>
__global__ __launch_bounds__(512, 4) void gemm_nt2(
    const void* __restrict__ Av, const unsigned short* __restrict__ Bt,
    unsigned short* __restrict__ Cb, void* __restrict__ Out, size_t outOff,
    const float* __restrict__ atS, const float* __restrict__ atD,
    float* __restrict__ asrc, float* __restrict__ adst,
    const int* __restrict__ flags, int M, int Nn, int K)
{
  __shared__ unsigned short Als[128 * 64];   // 16 KB
  __shared__ unsigned short Bls[256 * 64];   // 32 KB
  __shared__ float sdot[2][128];             // 1 KB (DOTS only)
  const int tid = threadIdx.x, lane = tid & 63, wid = tid >> 6;   // 8 waves
  const int wr = wid >> 2, wc = wid & 3;     // 2x4 wave grid, 64x64 each
  const int rowBase = blockIdx.y * 128, colBase = blockIdx.x * 256;
  const int fb = flags[0];

  const int srow = (lane >> 3), sg = lane & 7;
  const int sgx = sg ^ srow;                 // inverse-swizzled source granule

  f32x4 acc[4][4] = {};

  for (int kt = 0; kt < K; kt += 64) {
    // ---- stage A: 16 chunks (1KB = 8 rows), 2 per wave ----
    if (AMODE == 1 && !fb) {
      const float* Af = (const float*)Av;
#pragma unroll
      for (int i = 0; i < 2; ++i) {
        int row = wid * 16 + i * 8 + srow;
        int gr = rowBase + row; if (gr > M - 1) gr = M - 1;
        const float* sp = Af + (size_t)gr * K + kt + sg * 8;   // linear coalesced
        float4 lo = *(const float4*)sp;
        float4 hi = *(const float4*)(sp + 4);
        union { unsigned short us[8]; int4 v; } cv;
        cv.us[0] = f2b(lo.x); cv.us[1] = f2b(lo.y); cv.us[2] = f2b(lo.z); cv.us[3] = f2b(lo.w);
        cv.us[4] = f2b(hi.x); cv.us[5] = f2b(hi.y); cv.us[6] = f2b(hi.z); cv.us[7] = f2b(hi.w);
        *(int4*)(Als + row * 64 + (sgx << 3)) = cv.v;          // swizzled ds_write
      }
    } else {
      const unsigned short* Ab = (const unsigned short*)Av;
#pragma unroll
      for (int i = 0; i < 2; ++i) {
        int row = wid * 16 + i * 8 + srow;
        int gr = rowBase + row;
        if (AMODE == 1 && gr > M - 1) gr = M - 1;   // external input: clamp
        gld16(Ab + (size_t)gr * K + kt + (sgx << 3), Als + (wid * 2 + i) * 512);
      }
    }
    // ---- stage B: 32 chunks, 4 per wave ----
#pragma unroll
    for (int i = 0; i < 4; ++i) {
      int row = wid * 32 + i * 8 + srow;
      gld16(Bt + (size_t)(colBase + row) * K + kt + (sgx << 3), Bls + (wid * 4 + i) * 512);
    }
    __syncthreads();

    bf16x8 af[4], bfr[4];
#pragma unroll
    for (int ks = 0; ks < 2; ++ks) {
      int gl = ks * 4 + (lane >> 4);
      int gx = gl ^ (lane & 7);        // row&7 == lane&7 for fragment rows
#pragma unroll
      for (int mi = 0; mi < 4; ++mi) {
        int row = wr * 64 + mi * 16 + (lane & 15);
        af[mi] = *(const bf16x8*)(Als + row * 64 + (gx << 3));
      }
#pragma unroll
      for (int ni = 0; ni < 4; ++ni) {
        int row = wc * 64 + ni * 16 + (lane & 15);
        bfr[ni] = *(const bf16x8*)(Bls + row * 64 + (gx << 3));
      }
#pragma unroll
      for (int mi = 0; mi < 4; ++mi)
#pragma unroll
        for (int ni = 0; ni < 4; ++ni)
          acc[mi][ni] = __builtin_amdgcn_mfma_f32_16x16x32_bf16(af[mi], bfr[ni], acc[mi][ni], 0, 0, 0);
    }
    __syncthreads();
  }

  // C/D: col = lane&15, row = (lane>>4)*4 + reg
#pragma unroll
  for (int mi = 0; mi < 4; ++mi) {
    int r0 = rowBase + wr * 64 + mi * 16 + (lane >> 4) * 4;
#pragma unroll
    for (int ni = 0; ni < 4; ++ni) {
      int c = colBase + wc * 64 + ni * 16 + (lane & 15);
#pragma unroll
      for (int v = 0; v < 4; ++v) {
        int r = r0 + v;
        if (r < M) {
          size_t idx = (size_t)r * Nn + c;
          float x = acc[mi][ni][v];
          if (EPI) x = x > 0.f ? x : expm1f(x);
          if (OUTMODE == 0) Cb[idx] = f2b(x);
          else {
            if (fb) ((unsigned short*)Out)[outOff + idx] = f2b(x);
            else    ((float*)Out)[outOff + idx] = x;
          }
        }
      }
    }
  }

  // ---- fused rowdots epilogue (xp1 only): asrc/adst from f32 accumulators ----
  if (DOTS) {
    if (tid < 128) { sdot[0][tid] = 0.f; sdot[1][tid] = 0.f; }
    __syncthreads();
    float vS[4], vD[4];
#pragma unroll
    for (int ni = 0; ni < 4; ++ni) {
      int c = colBase + wc * 64 + ni * 16 + (lane & 15);
      vS[ni] = atS[c]; vD[ni] = atD[c];
    }
#pragma unroll
    for (int mi = 0; mi < 4; ++mi) {
#pragma unroll
      for (int v = 0; v < 4; ++v) {
        float ps = 0.f, pd = 0.f;
#pragma unroll
        for (int ni = 0; ni < 4; ++ni) {
          ps += acc[mi][ni][v] * vS[ni];
          pd += acc[mi][ni][v] * vD[ni];
        }
#pragma unroll
        for (int off = 1; off < 16; off <<= 1) {
          ps += __shfl_xor(ps, off);
          pd += __shfl_xor(pd, off);
        }
        if ((lane & 15) == 0) {
          int rl = wr * 64 + mi * 16 + (lane >> 4) * 4 + v;
          atomicAdd(&sdot[0][rl], ps);   // combine the 4 column-waves
          atomicAdd(&sdot[1][rl], pd);
        }
      }
    }
    __syncthreads();
    if (tid < 128) {
      int r = rowBase + tid;
      if (r < M) { asrc[r] = sdot[0][tid]; adst[r] = sdot[1][tid]; }
    }
  }
}

// ---- agg layer 1: wave/node, 16 gathers in flight, denominator in-loop ----
__global__ __launch_bounds__(256) void agg_elu2(
    const unsigned short* __restrict__ xp,
    const float* __restrict__ asrc, const float* __restrict__ adst,
    const int* __restrict__ srcP, const int* __restrict__ offs,
    unsigned short* __restrict__ hout, int N)
{
  __shared__ int   sS[4][64];
  __shared__ float sW[4][64];
  int wid = threadIdx.x >> 6, lane = threadIdx.x & 63;
  int node = blockIdx.x * 4 + wid;
  if (node >= N) return;
  const float ad = adst[node];
  int s0 = offs[node], s1 = offs[node + 1];
  float a0 = 0.f, a1 = 0.f, a2 = 0.f, a3 = 0.f, den = 0.f;
  for (int base = s0; base < s1; base += 64) {
    int cnt = s1 - base; if (cnt > 64) cnt = 64;
    if (lane < cnt) {
      int sv = srcP[base + lane];
      sS[wid][lane] = sv;
      sW[wid][lane] = edgew(asrc[sv] + ad);
    }
    asm volatile("s_waitcnt lgkmcnt(0)" ::: "memory");   // wave-local LDS RAW fence
    int j = 0;
    for (; j + 16 <= cnt; j += 16) {          // 16 gathers in flight
      ushort4 u[16];
#pragma unroll
      for (int q = 0; q < 16; ++q)
        u[q] = *(const ushort4*)(xp + (size_t)sS[wid][j + q] * HIDD + lane * 4);
#pragma unroll
      for (int q = 0; q < 16; ++q) {
        float wv = sW[wid][j + q];
        den += wv;
        a0 += wv * b2f(u[q].x); a1 += wv * b2f(u[q].y);
        a2 += wv * b2f(u[q].z); a3 += wv * b2f(u[q].w);
      }
    }
    for (; j + 8 <= cnt; j += 8) {
      ushort4 u[8];
#pragma unroll
      for (int q = 0; q < 8; ++q)
        u[q] = *(const ushort4*)(xp + (size_t)sS[wid][j + q] * HIDD + lane * 4);
#pragma unroll
      for (int q = 0; q < 8; ++q) {
        float wv = sW[wid][j + q];
        den += wv;
        a0 += wv * b2f(u[q].x); a1 += wv * b2f(u[q].y);
        a2 += wv * b2f(u[q].z); a3 += wv * b2f(u[q].w);
      }
    }
    for (; j < cnt; ++j) {
      int   sv = sS[wid][j];
      float wv = sW[wid][j];
      den += wv;
      ushort4 u = *(const ushort4*)(xp + (size_t)sv * HIDD + lane * 4);
      a0 += wv * b2f(u.x); a1 += wv * b2f(u.y); a2 += wv * b2f(u.z); a3 += wv * b2f(u.w);
    }
  }
  float inv = 1.f / (den + 1e-16f);
  float r0 = a0 * inv, r1 = a1 * inv, r2 = a2 * inv, r3 = a3 * inv;
  r0 = r0 > 0.f ? r0 : expm1f(r0);
  r1 = r1 > 0.f ? r1 : expm1f(r1);
  r2 = r2 > 0.f ? r2 : expm1f(r2);
  r3 = r3 > 0.f ? r3 : expm1f(r3);
  ushort4 o; o.x = f2b(r0); o.y = f2b(r1); o.z = f2b(r2); o.w = f2b(r3);
  *(ushort4*)(hout + (size_t)node * HIDD + lane * 4) = o;
}

// ---- h2 = h1 @ W2 ([N,256]x[256,32]) -> adaptive out + bf16 copy ----
__global__ __launch_bounds__(256) void gemm_h2(
    const unsigned short* __restrict__ H1, const float* __restrict__ W2f,
    void* __restrict__ Out, unsigned short* __restrict__ h2b,
    const int* __restrict__ flags, int M)
{
  const int fb = flags[0];
  __shared__ float Bs[HIDD][33];
  __shared__ float As[8][HIDD];
  int tid = threadIdx.x;
  int tx = tid & 31, ty = tid >> 5;
  int row0 = blockIdx.x * 8;
#pragma unroll
  for (int j = 0; j < 8; ++j) {            // W2 (256x32 f32) via float4
    int idx4 = tid + 256 * j;              // 2048 float4s
    float4 v = *(const float4*)(W2f + idx4 * 4);
    int k = idx4 >> 3, c = (idx4 & 7) * 4;
    Bs[k][c] = v.x; Bs[k][c + 1] = v.y; Bs[k][c + 2] = v.z; Bs[k][c + 3] = v.w;
  }
  {
    int flat = tid * 8;                    // 8 rows x 256 = 2048 bf16, 16B/thread
    int r = flat >> 8, k = flat & 255;
    int gr = row0 + r;
    if (gr < M) {
      ushort4 lo = *(const ushort4*)(H1 + (size_t)gr * HIDD + k);
      ushort4 hi = *(const ushort4*)(H1 + (size_t)gr * HIDD + k + 4);
      As[r][k] = b2f(lo.x); As[r][k + 1] = b2f(lo.y); As[r][k + 2] = b2f(lo.z); As[r][k + 3] = b2f(lo.w);
      As[r][k + 4] = b2f(hi.x); As[r][k + 5] = b2f(hi.y); As[r][k + 6] = b2f(hi.z); As[r][k + 7] = b2f(hi.w);
    } else {
#pragma unroll
      for (int q = 0; q < 8; ++q) As[r][k + q] = 0.f;
    }
  }
  __syncthreads();
  float acc = 0.f;
#pragma unroll 8
  for (int k = 0; k < HIDD; ++k) acc += As[ty][k] * Bs[k][tx];
  int row = row0 + ty;
  if (row < M) {
    size_t idx = (size_t)row * OUTD + tx;
    if (fb) ((unsigned short*)Out)[idx] = f2b(acc);
    else    ((float*)Out)[idx] = acc;
    h2b[idx] = f2b(acc);
  }
}

// ---- agg layer 2 on h2 [N,32] bf16 -> g2pad [N][64] (upper 32 zeroed) ----
__global__ __launch_bounds__(256) void agg_small(
    const unsigned short* __restrict__ h2b,
    const float* __restrict__ asrc, const float* __restrict__ adst,
    const int* __restrict__ srcP, const int* __restrict__ offs,
    unsigned short* __restrict__ g2pad, int N)
{
  int wid = threadIdx.x >> 6, lane = threadIdx.x & 63;
  int node = blockIdx.x * 4 + wid;
  if (node >= N) return;
  int grp = lane >> 4, cl = lane & 15;
  const float ad = adst[node];
  int s0 = offs[node], s1 = offs[node + 1];
  float a0 = 0.f, a1 = 0.f, den = 0.f;
  for (int e = s0 + grp; e < s1; e += 4) {
    int   sv = srcP[e];          // uniform across the 16-lane group (broadcast)
    float wv = edgew(asrc[sv] + ad);
    den += wv;
    ushort2 u = *(const ushort2*)(h2b + (size_t)sv * OUTD + cl * 2);
    a0 += wv * b2f(u.x);
    a1 += wv * b2f(u.y);
  }
  a0 += __shfl_xor(a0, 16); a0 += __shfl_xor(a0, 32);
  a1 += __shfl_xor(a1, 16); a1 += __shfl_xor(a1, 32);
  den += __shfl_xor(den, 16); den += __shfl_xor(den, 32);
  if (grp == 0) {
    float inv = 1.f / (den + 1e-16f);
    ushort2 o; o.x = f2b(a0 * inv); o.y = f2b(a1 * inv);
    *(ushort2*)(g2pad + (size_t)node * 64 + cl * 2) = o;
  } else if (grp == 1) {
    *(ushort2*)(g2pad + (size_t)node * 64 + 32 + cl * 2) = make_ushort2(0, 0);  // K-pad
  }
}

extern "C" void kernel_launch(void* const* d_in, const int* in_sizes, int n_in,
                              void* d_out, int out_size, void* d_ws, size_t ws_size,
                              hipStream_t stream)
{
  const void*         feat = d_in[0];
  const unsigned int* eidx = (const unsigned int*)d_in[1];
  const void*         W1   = d_in[2];
  const void*         W2   = d_in[3];
  const void*         aS   = d_in[4];
  const void*         aD   = d_in[5];

  const int N = in_sizes[0] / INDIM;
  const int E = in_sizes[1] / 2;
  const int M_pad = ((N + 127) / 128) * 128;
  const int nslab = (N + SLABN - 1) / SLABN;   // 196 for N=100000; must be <= 256
  const int npb = (E + PCH - 1) / PCH;

  char* w = (char*)d_ws;
  auto alloc = [&](size_t bytes) -> char* {
    char* p = w; w += (bytes + 255) & ~(size_t)255; return p;
  };
  unsigned short* H     = (unsigned short*)alloc((size_t)M_pad * HIDD * 2);  // h1 / h3
  unsigned short* P     = (unsigned short*)alloc((size_t)M_pad * HIDD * 2);  // xp1
  unsigned short* h2b   = (unsigned short*)alloc((size_t)N * OUTD * 2);      // h2 bf16
  unsigned short* g2pad = (unsigned short*)alloc((size_t)M_pad * 64 * 2);    // agg(h2), K-padded
  float* asrc = (float*)alloc((size_t)N * 4);
  float* adst = (float*)alloc((size_t)N * 4);
  int*   srcP = (int*)alloc((size_t)E * 4);     // CSR-ordered edge src
  uint2* part = (uint2*)alloc((size_t)E * 8);   // slab-partitioned (src,dst)
  int*   offs = (int*)alloc((size_t)(N + 1) * 4);
  int*   bcnt = (int*)alloc((size_t)npb * 256 * 4);
  int*   slabOff = (int*)alloc(257 * 4);
  unsigned short* W1b   = (unsigned short*)alloc((size_t)INDIM * HIDD * 2); // [512][256]
  unsigned short* W1tb  = (unsigned short*)alloc((size_t)INDIM * HIDD * 2); // [256][512]
  unsigned short* W2b64 = (unsigned short*)alloc((size_t)HIDD * 64 * 2);    // [256][64]
  float* W2f  = (float*)alloc((size_t)HIDD * OUTD * 4);
  float* atS  = (float*)alloc((size_t)HIDD * 4);
  float* atD  = (float*)alloc((size_t)HIDD * 4);
  int*   flags = (int*)alloc(64);

  probe_kernel<<<1, 256, 0, stream>>>((const unsigned int*)feat, eidx, flags);

  // CSR build: radix by dst-slab (512-node slabs), slab-local CSR in LDS
  cnt_kernel<<<npb, 256, 0, stream>>>(eidx, bcnt, E, flags);
  bscan_kernel<<<1, 256, 0, stream>>>(bcnt, slabOff, npb);
  scat_kernel<<<npb, 256, 0, stream>>>(eidx, bcnt, slabOff, part, E, flags);
  slabcsr_kernel<<<nslab, 256, 0, stream>>>(part, slabOff, offs, srcP, N, nslab);

  prep_weights<<<512, 256, 0, stream>>>(W1, W2, aS, aD, W1b, W1tb, W2f, W2b64, atS, atD, flags);

  const int mb = (N + 127) / 128;

  // xp1 = feat @ W1 (+ fused rowdots: asrc/adst from f32 accumulators)
  gemm_nt2<1, 0, 0, 1><<<dim3(1, mb), 512, 0, stream>>>(
      feat, W1tb, P, nullptr, 0, atS, atD, asrc, adst, flags, N, HIDD, INDIM);

  // GAT layer 1: h1 = elu(agg(xp1)/denom)
  agg_elu2<<<(N + 3) / 4, 256, 0, stream>>>(P, asrc, adst, srcP, offs, H, N);

  // h2 = h1 @ W2 -> output 0 (+ bf16 copy for layer-2 agg)
  gemm_h2<<<(N + 7) / 8, 256, 0, stream>>>(H, W2f, d_out, h2b, flags, N);

  // GAT layer 2, commuted: g2 = agg(h2) [N,32->64pad]
  agg_small<<<(N + 3) / 4, 256, 0, stream>>>(h2b, asrc, adst, srcP, offs, g2pad, N);

  // h3 = elu(g2 @ W2^T) via MFMA GEMM (single K-step, BN=256)
  gemm_nt2<0, 0, 1, 0><<<dim3(1, mb), 512, 0, stream>>>(
      g2pad, W2b64, H, nullptr, 0, nullptr, nullptr, nullptr, nullptr,
      flags, N, HIDD, 64);

  // h4 = h3 @ W1^T -> output 1 (adaptive)
  gemm_nt2<0, 1, 0, 0><<<dim3(2, mb), 512, 0, stream>>>(
      H, W1b, nullptr, d_out, (size_t)N * OUTD, nullptr, nullptr, nullptr, nullptr,
      flags, N, INDIM, HIDD);
}